// Round 5
// baseline (1000.690 us; speedup 1.0000x reference)
//
#include <hip/hip_runtime.h>
#include <hip/hip_bf16.h>
#include <stdint.h>

#define BB 4
#define SS 1024
#define DIM 2048
#define NH 16
#define QR 1024
#define KVR 512
#define NOPE 128
#define ROPE 64
#define VH 128
#define QKH 192
#define NTOK 4096

static constexpr float SCALE_ = 0.07216878364870322f; // 192^-0.5
static constexpr float EPS_ = 1e-6f;

typedef unsigned short u16;
typedef unsigned int u32;
using f32x4  = __attribute__((ext_vector_type(4))) float;
using bf16x8 = __attribute__((ext_vector_type(8))) __bf16;

#define MFMA16 __builtin_amdgcn_mfma_f32_16x16x32_bf16

__device__ __forceinline__ u16 f2b(float f) {
  u32 u = __float_as_uint(f);
  u32 r = u + 0x7fffu + ((u >> 16) & 1u);   // RNE
  return (u16)(r >> 16);
}
__device__ __forceinline__ u32 pk2(float a, float b) {
  return (u32)f2b(a) | ((u32)f2b(b) << 16);
}
__device__ __forceinline__ float b2f(u32 hi16) {
  return __uint_as_float(hi16 << 16);
}

// ---------------- f32 -> bf16 convert (8 elems/thread) ----------------
__global__ __launch_bounds__(256) void cvt_bf16(const float* __restrict__ in,
                                                u16* __restrict__ out, int n) {
  int i = (blockIdx.x * 256 + threadIdx.x) * 8;
  if (i >= n) return;
  float4 a = *(const float4*)&in[i];
  float4 b = *(const float4*)&in[i + 4];
  uint4 o;
  o.x = pk2(a.x, a.y); o.y = pk2(a.z, a.w);
  o.z = pk2(b.x, b.y); o.w = pk2(b.z, b.w);
  *(uint4*)&out[i] = o;
}

// ---------------- wkv_b split: wb_k transposed per head, wb_v straight ----------------
__global__ __launch_bounds__(256) void prep_wkvb(const float* __restrict__ w,
                                                 u16* __restrict__ wbkt,
                                                 u16* __restrict__ wbv) {
  int idx = blockIdx.x * 256 + threadIdx.x;   // over 16*256*512
  int c = idx & 511;
  int rowh = idx >> 9;
  int h = rowh >> 8;
  int dr = rowh & 255;
  float v = w[idx];
  if (dr < NOPE) wbkt[((h * KVR + c) << 7) + dr] = f2b(v);           // (NH,512,128)
  else           wbv[((h * VH + (dr - NOPE)) << 9) + c] = f2b(v);    // (NH,128,512)
}

// ---------------- RMSNorm over 1024 (q path) ----------------
__global__ __launch_bounds__(256) void rms_q_kernel(const float* __restrict__ X,
                                                    const float* __restrict__ w,
                                                    u16* __restrict__ out) {
  int r = blockIdx.x, tid = threadIdx.x;
  const float4 v = *(const float4*)&X[(long)r * QR + tid * 4];
  float ss = v.x * v.x + v.y * v.y + v.z * v.z + v.w * v.w;
  for (int m = 1; m < 64; m <<= 1) ss += __shfl_xor(ss, m);
  __shared__ float red[4];
  if ((tid & 63) == 0) red[tid >> 6] = ss;
  __syncthreads();
  float tot = red[0] + red[1] + red[2] + red[3];
  float sc = rsqrtf(tot / QR + EPS_);
  float4 wv = *(const float4*)&w[tid * 4];
  uint2 o;
  o.x = pk2(v.x * sc * wv.x, v.y * sc * wv.y);
  o.y = pk2(v.z * sc * wv.z, v.w * sc * wv.w);
  *(uint2*)&out[(long)r * QR + tid * 4] = o;
}

// ---------------- q post (bf16 input): split nope / rope(pe)*SCALE, head-major ----------------
__global__ __launch_bounds__(256) void post_q_kernel(const u16* __restrict__ C2,
                                                     const float* __restrict__ fc,
                                                     const float* __restrict__ fs,
                                                     u16* __restrict__ qn,
                                                     u16* __restrict__ qp) {
  int r = blockIdx.x, tid = threadIdx.x;
  int s = r & (SS - 1);
  const u16* row = C2 + (long)r * (NH * QKH);
  for (int j = tid; j < NH * QKH / 2; j += 256) {
    int col = j * 2;
    int h = col / QKH;
    int dd = col - h * QKH;
    u32 pair = *(const u32*)&row[col];
    if (dd < NOPE) {
      *(u32*)&qn[((long)h * NTOK + r) * NOPE + dd] = pair;   // already bf16
    } else {
      float x0 = b2f(pair & 0xffffu), x1 = b2f(pair >> 16);
      int jr = (dd - NOPE) >> 1;
      float c = fc[s * 32 + jr], sn = fs[s * 32 + jr];
      *(u32*)&qp[((long)h * NTOK + r) * ROPE + (dd - NOPE)] =
          pk2((x0 * c - x1 * sn) * SCALE_, (x0 * sn + x1 * c) * SCALE_);
    }
  }
}

// ---------------- kv post: rmsnorm(512) -> kv_sw (XOR-swizzled) + kv^T, rope k_pe_sw ----------------
// Swizzle: element index d' = d ^ ((t&7)<<3) within each row.
__global__ __launch_bounds__(256) void post_kv_kernel(const float* __restrict__ C3,
                                                      const float* __restrict__ w,
                                                      const float* __restrict__ fc,
                                                      const float* __restrict__ fs,
                                                      u16* __restrict__ kv_sw,
                                                      u16* __restrict__ kvt,
                                                      u16* __restrict__ kpe_sw) {
  int r = blockIdx.x, tid = threadIdx.x;
  int b = r >> 10, t = r & (SS - 1);
  const float* row = C3 + (long)r * 576;
  float2 v = *(const float2*)&row[tid * 2];
  float ss = v.x * v.x + v.y * v.y;
  for (int m = 1; m < 64; m <<= 1) ss += __shfl_xor(ss, m);
  __shared__ float red[4];
  if ((tid & 63) == 0) red[tid >> 6] = ss;
  __syncthreads();
  float tot = red[0] + red[1] + red[2] + red[3];
  float sc = rsqrtf(tot / KVR + EPS_);
  int c = tid * 2;
  int xm = (t & 7) << 3;
  float y0 = v.x * sc * w[c], y1 = v.y * sc * w[c + 1];
  *(u32*)&kv_sw[((long)b * SS + t) * KVR + (c ^ xm)] = pk2(y0, y1);
  kvt[((long)b * KVR + c) * SS + t] = f2b(y0);
  kvt[((long)b * KVR + c + 1) * SS + t] = f2b(y1);
  if (tid < 32) {
    float x0 = row[KVR + tid * 2], x1 = row[KVR + tid * 2 + 1];
    float cc = fc[t * 32 + tid], sn = fs[t * 32 + tid];
    *(u32*)&kpe_sw[((long)b * SS + t) * ROPE + ((tid * 2) ^ xm)] =
        pk2(x0 * cc - x1 * sn, x0 * sn + x1 * cc);
  }
}

// ---------------- GEMM: C(M,N) = A(M,K) * B(N,K)^T, bf16 in, f32/bf16 out ----------------
template <bool CBF16>
__global__ __launch_bounds__(256) void gemm_bt(const u16* __restrict__ Ag,
                                               const u16* __restrict__ Bg,
                                               void* __restrict__ Cg,
                                               int M, int N, int K,
                                               int lda, int ldb, int ldc,
                                               long sA, long sB, long sC,
                                               float oscale) {
  const u16* A = Ag + (long)blockIdx.z * sA;
  const u16* Bm = Bg + (long)blockIdx.z * sB;
  const int row0 = blockIdx.y * 128;
  const int col0 = blockIdx.x * 128;
  const int tid = threadIdx.x;
  const int wave = tid >> 6, lane = tid & 63;
  const int g = lane >> 4, r = lane & 15;
  const int wr = wave >> 1, wc = wave & 1;

  __shared__ u16 As[2][128 * 32];
  __shared__ u16 Bs[2][128 * 32];

  f32x4 acc[4][4] = {};
  const int nk = K >> 5;

  auto stage = [&](int kt, int p) {
    int k0 = kt << 5;
#pragma unroll
    for (int j = 0; j < 2; ++j) {
      int ldsoff = (j * 4096 + wave * 1024) >> 1;
      int rowi = j * 64 + wave * 16 + (lane >> 2);
      int coli = (lane & 3) << 3;
      const u16* ga = A + (long)(row0 + rowi) * lda + k0 + coli;
      __builtin_amdgcn_global_load_lds(
          (const __attribute__((address_space(1))) void*)ga,
          (__attribute__((address_space(3))) void*)(&As[p][ldsoff]), 16, 0, 0);
      int rb = col0 + rowi; if (rb > N - 1) rb = N - 1;
      const u16* gb = Bm + (long)rb * ldb + k0 + coli;
      __builtin_amdgcn_global_load_lds(
          (const __attribute__((address_space(1))) void*)gb,
          (__attribute__((address_space(3))) void*)(&Bs[p][ldsoff]), 16, 0, 0);
    }
  };

  stage(0, 0);
  for (int kt = 0; kt < nk; ++kt) {
    __syncthreads();
    if (kt + 1 < nk) stage(kt + 1, (kt + 1) & 1);
    const int p = kt & 1;
    bf16x8 af[4], bf[4];
#pragma unroll
    for (int i = 0; i < 4; i++) {
      af[i] = *(const bf16x8*)&As[p][(wr * 64 + i * 16 + r) * 32 + g * 8];
      bf[i] = *(const bf16x8*)&Bs[p][(wc * 64 + i * 16 + r) * 32 + g * 8];
    }
#pragma unroll
    for (int i = 0; i < 4; i++)
#pragma unroll
      for (int j = 0; j < 4; j++)
        acc[i][j] = MFMA16(af[i], bf[j], acc[i][j], 0, 0, 0);
  }

#pragma unroll
  for (int i = 0; i < 4; i++)
#pragma unroll
    for (int j = 0; j < 4; j++) {
      int rowb = row0 + wr * 64 + i * 16 + g * 4;
      int colc = col0 + wc * 64 + j * 16 + r;
      if (colc < N) {
        if constexpr (CBF16) {
          u16* C = (u16*)Cg + (long)blockIdx.z * sC;
#pragma unroll
          for (int e = 0; e < 4; e++)
            C[(long)(rowb + e) * ldc + colc] = f2b(acc[i][j][e] * oscale);
        } else {
          float* C = (float*)Cg + (long)blockIdx.z * sC;
#pragma unroll
          for (int e = 0; e < 4; e++)
            C[(long)(rowb + e) * ldc + colc] = acc[i][j][e] * oscale;
        }
      }
    }
}

// ---------------- flash attention v4 ----------------
// 512 blocks: one 128-row chunk each, batch pinned to XCD pair, balanced j-map,
// big chunks first. 8 waves: QK per-wave 16 rows (Q in regs, dual chains);
// PV all-rows x own 64 V-cols. Ks and P double-buffered -> ONE barrier/tile
// (__syncthreads_and returns block-wide "no row max changed" -> skip rescale).
__global__ __launch_bounds__(512) void attn_kernel(
    const u16* __restrict__ q_lat, const u16* __restrict__ q_pe,
    const u16* __restrict__ kv_sw, const u16* __restrict__ kvt,
    const u16* __restrict__ kpe_sw, u16* __restrict__ o_lat) {
  const int bid = blockIdx.x;
  const int xcd = bid & 7;
  const int b = xcd >> 1;
  const int idx = bid >> 3;                       // 0..63
  const int h = idx & 15;
  const int jj = idx >> 4;                        // 0..3
  const int j = (jj << 1) | ((xcd & 1) ^ (jj & 1)); // balanced across XCD pair
  const int jc = 7 - j;                           // big chunks at low bid
  const int qa = jc * 128;
  const int nt = (qa >> 5) + 4;

  const int wv = threadIdx.x >> 6, lane = threadIdx.x & 63;
  const int g = lane >> 4, r = lane & 15;
  const int xm = (r & 7) << 3;

  __shared__ __attribute__((aligned(16))) u16 Ks[2][32 * 512];   // 64 KB dbuf
  __shared__ __attribute__((aligned(16))) u16 P[2][128][40];     // 20 KB dbuf
  __shared__ __attribute__((aligned(16))) float alphab[2][128];
  __shared__ __attribute__((aligned(16))) float lbuf[128];

  const u16* KVg = kv_sw + (long)b * SS * KVR;
  const u16* KPg = kpe_sw + (long)b * SS * ROPE;
  const u16* KT  = kvt + (long)b * KVR * SS;

  const int q_row = qa + wv * 16 + r;
  const u16* Q  = q_lat + ((long)h * NTOK + (long)b * SS + q_row) * KVR;
  const u16* Qp = q_pe  + ((long)h * NTOK + (long)b * SS + q_row) * ROPE;
  bf16x8 qf[16], qp[2];
#pragma unroll
  for (int c = 0; c < 16; ++c) qf[c] = *(const bf16x8*)&Q[c * 32 + g * 8];
  qp[0] = *(const bf16x8*)&Qp[g * 8];
  qp[1] = *(const bf16x8*)&Qp[32 + g * 8];

  f32x4 acc[8][4];
#pragma unroll
  for (int i = 0; i < 8; i++)
#pragma unroll
    for (int jn = 0; jn < 4; jn++) acc[i][jn] = f32x4{0.f, 0.f, 0.f, 0.f};
  float m_run = -1e30f, l_run = 0.f;

  auto stage = [&](int p, int t0) {
#pragma unroll
    for (int i = 0; i < 4; ++i) {
      int row = wv * 4 + i;
      const u16* ga = KVg + (long)(t0 + row) * KVR + lane * 8;
      __builtin_amdgcn_global_load_lds(
          (const __attribute__((address_space(1))) void*)ga,
          (__attribute__((address_space(3))) void*)(&Ks[p][row * 512]), 16, 0, 0);
    }
  };

  stage(0, 0);
  __syncthreads();
  int cur = 0;

  for (int tt = 0; tt < nt; ++tt) {
    const int t0 = tt << 5;
    if (tt + 1 < nt) stage(cur ^ 1, t0 + 32);   // lands by next tile's barrier

    // prefetch V (own 64 cols) and k_pe for this tile
    bf16x8 vf[4];
#pragma unroll
    for (int nc = 0; nc < 4; ++nc)
      vf[nc] = *(const bf16x8*)&KT[(long)(wv * 64 + nc * 16 + r) * SS + t0 + g * 8];
    bf16x8 kpA[2], kpB[2];
#pragma unroll
    for (int c = 0; c < 2; ++c) {
      int ix = (c * 32 + g * 8) ^ xm;
      kpA[c] = *(const bf16x8*)&KPg[(long)(t0 + r) * ROPE + ix];
      kpB[c] = *(const bf16x8*)&KPg[(long)(t0 + 16 + r) * ROPE + ix];
    }

    // QK^T: two independent accumulate chains per key-row-half
    f32x4 sA0 = {0.f,0.f,0.f,0.f}, sB0 = {0.f,0.f,0.f,0.f};
    f32x4 sA1 = {0.f,0.f,0.f,0.f}, sB1 = {0.f,0.f,0.f,0.f};
#pragma unroll
    for (int c = 0; c < 16; c += 2) {
      int ix0 = (c * 32 + g * 8) ^ xm;
      int ix1 = ((c + 1) * 32 + g * 8) ^ xm;
      bf16x8 k00 = *(const bf16x8*)&Ks[cur][r * 512 + ix0];
      bf16x8 k10 = *(const bf16x8*)&Ks[cur][(16 + r) * 512 + ix0];
      bf16x8 k01 = *(const bf16x8*)&Ks[cur][r * 512 + ix1];
      bf16x8 k11 = *(const bf16x8*)&Ks[cur][(16 + r) * 512 + ix1];
      sA0 = MFMA16(k00, qf[c], sA0, 0, 0, 0);
      sA1 = MFMA16(k10, qf[c], sA1, 0, 0, 0);
      sB0 = MFMA16(k01, qf[c + 1], sB0, 0, 0, 0);
      sB1 = MFMA16(k11, qf[c + 1], sB1, 0, 0, 0);
    }
    sA0 = MFMA16(kpA[0], qp[0], sA0, 0, 0, 0);
    sB0 = MFMA16(kpA[1], qp[1], sB0, 0, 0, 0);
    sA1 = MFMA16(kpB[0], qp[0], sA1, 0, 0, 0);
    sB1 = MFMA16(kpB[1], qp[1], sB1, 0, 0, 0);
    f32x4 st0 = sA0 + sB0, st1 = sA1 + sB1;

    // softmax (scores pre-scaled; lane owns q_row, keys {t0+g*4+i, t0+16+g*4+i})
    float sv[8];
    float smax = -1e30f;
#pragma unroll
    for (int i = 0; i < 4; i++) {
      int t = t0 + g * 4 + i;
      sv[i]     = (t      <= q_row) ? st0[i] : -1e30f;
      sv[4 + i] = (t + 16 <= q_row) ? st1[i] : -1e30f;
      smax = fmaxf(smax, fmaxf(sv[i], sv[4 + i]));
    }
    smax = fmaxf(smax, __shfl_xor(smax, 16));
    smax = fmaxf(smax, __shfl_xor(smax, 32));
    float m_new = fmaxf(m_run, smax);
    int st_pred = (m_new == m_run);
    float alpha = __expf(m_run - m_new);
    float p[8], ps = 0.f;
#pragma unroll
    for (int i = 0; i < 8; i++) {
      p[i] = (sv[i] < -1e29f) ? 0.f : __expf(sv[i] - m_new);
      ps += p[i];
    }
    ps += __shfl_xor(ps, 16);
    ps += __shfl_xor(ps, 32);
    l_run = l_run * alpha + ps;
    m_run = m_new;

    uint2 pw0, pw1;
    pw0.x = pk2(p[0], p[1]); pw0.y = pk2(p[2], p[3]);
    pw1.x = pk2(p[4], p[5]); pw1.y = pk2(p[6], p[7]);
    *(uint2*)&P[cur][wv * 16 + r][g * 4]      = pw0;
    *(uint2*)&P[cur][wv * 16 + r][16 + g * 4] = pw1;
    if (g == 0) alphab[cur][wv * 16 + r] = alpha;

    int stable = __syncthreads_and(st_pred);   // single barrier per tile

    // ---- PV: all 128 rows x own 64 cols ----
    if (stable) {
#pragma unroll
      for (int mc = 0; mc < 8; ++mc) {
        bf16x8 pa = *(const bf16x8*)&P[cur][mc * 16 + r][g * 8];
#pragma unroll
        for (int nc = 0; nc < 4; ++nc)
          acc[mc][nc] = MFMA16(pa, vf[nc], acc[mc][nc], 0, 0, 0);
      }
    } else {
#pragma unroll
      for (int mc = 0; mc < 8; ++mc) {
        bf16x8 pa = *(const bf16x8*)&P[cur][mc * 16 + r][g * 8];
        f32x4 a4 = *(const f32x4*)&alphab[cur][mc * 16 + g * 4];
#pragma unroll
        for (int nc = 0; nc < 4; ++nc) {
          f32x4 t = acc[mc][nc] * a4;
          acc[mc][nc] = MFMA16(pa, vf[nc], t, 0, 0, 0);
        }
      }
    }
    cur ^= 1;
  }

  if (g == 0) lbuf[wv * 16 + r] = l_run;
  __syncthreads();
  u16* O = o_lat + ((long)h * NTOK + (long)b * SS + qa) * KVR;
#pragma unroll
  for (int mc = 0; mc < 8; ++mc) {
    f32x4 li = *(const f32x4*)&lbuf[mc * 16 + g * 4];
#pragma unroll
    for (int e = 0; e < 4; e++) li[e] = 1.f / li[e];
#pragma unroll
    for (int nc = 0; nc < 4; ++nc) {
      int col = wv * 64 + nc * 16 + r;
#pragma unroll
      for (int e = 0; e < 4; e++)
        O[(long)(mc * 16 + g * 4 + e) * KVR + col] = f2b(acc[mc][nc][e] * li[e]);
    }
  }
}

// ---------------- host launch ----------------
extern "C" void kernel_launch(void* const* d_in, const int* in_sizes, int n_in,
                              void* d_out, int out_size, void* d_ws, size_t ws_size,
                              hipStream_t stream) {
  (void)in_sizes; (void)n_in; (void)out_size; (void)ws_size;
  const float* x    = (const float*)d_in[0];
  const float* fc   = (const float*)d_in[2];
  const float* fs   = (const float*)d_in[3];
  const float* wqa  = (const float*)d_in[4];
  const float* qnw  = (const float*)d_in[5];
  const float* wqb  = (const float*)d_in[6];
  const float* wkva = (const float*)d_in[7];
  const float* kvnw = (const float*)d_in[8];
  const float* wkvb = (const float*)d_in[9];
  const float* wo   = (const float*)d_in[10];
  float* out = (float*)d_out;

  char* w = (char*)d_ws;
  size_t off = 0;
  auto alloc = [&](size_t bytes) {
    void* p = w + off;
    off += (bytes + 255) & ~(size_t)255;
    return p;
  };
  // ---- persistent region ----
  u16* wbkt   = (u16*)alloc((size_t)NH * KVR * NOPE * 2);
  u16* wbv    = (u16*)alloc((size_t)NH * VH * KVR * 2);
  u16* wo_b   = (u16*)alloc((size_t)DIM * DIM * 2);
  u16* qnope  = (u16*)alloc((size_t)NH * NTOK * NOPE * 2);
  u16* qpe    = (u16*)alloc((size_t)NH * NTOK * ROPE * 2);
  u16* kv_sw  = (u16*)alloc((size_t)BB * SS * KVR * 2);
  u16* kvt    = (u16*)alloc((size_t)BB * KVR * SS * 2);
  u16* kpe_sw = (u16*)alloc((size_t)BB * SS * ROPE * 2);
  u16* oflat  = (u16*)alloc((size_t)NTOK * DIM * 2);
  // ---- transient region, later overlaid by qlat/olat ----
  u16* qlat   = (u16*)(w + off);            // overlay base
  u16* olat   = qlat;                       // attention writes O in-place over Q
  u16* x_bf   = (u16*)alloc((size_t)NTOK * DIM * 2);
  u16* wqa_b  = (u16*)alloc((size_t)QR * DIM * 2);
  u16* wqb_b  = (u16*)alloc((size_t)NH * QKH * QR * 2);
  u16* wkva_b = (u16*)alloc((size_t)576 * DIM * 2);
  u16* qn     = (u16*)alloc((size_t)NTOK * QR * 2);
  float* C1   = (float*)alloc((size_t)NTOK * QR * 4);
  u16* C2b    = (u16*)alloc((size_t)NTOK * NH * QKH * 2);

  cvt_bf16<<<(NTOK * DIM) / 2048, 256, 0, stream>>>(x, x_bf, NTOK * DIM);
  cvt_bf16<<<(QR * DIM) / 2048, 256, 0, stream>>>(wqa, wqa_b, QR * DIM);
  cvt_bf16<<<(NH * QKH * QR) / 2048, 256, 0, stream>>>(wqb, wqb_b, NH * QKH * QR);
  cvt_bf16<<<(576 * DIM) / 2048, 256, 0, stream>>>(wkva, wkva_b, 576 * DIM);
  cvt_bf16<<<(DIM * DIM) / 2048, 256, 0, stream>>>(wo, wo_b, DIM * DIM);
  prep_wkvb<<<(NH * 256 * KVR) / 256, 256, 0, stream>>>(wkvb, wbkt, wbv);

  gemm_bt<false><<<dim3(QR / 128, NTOK / 128, 1), 256, 0, stream>>>(
      x_bf, wqa_b, C1, NTOK, QR, DIM, DIM, DIM, QR, 0, 0, 0, 1.f);
  rms_q_kernel<<<NTOK, 256, 0, stream>>>(C1, qnw, qn);
  gemm_bt<true><<<dim3(NH * QKH / 128, NTOK / 128, 1), 256, 0, stream>>>(
      qn, wqb_b, C2b, NTOK, NH * QKH, QR, QR, QR, NH * QKH, 0, 0, 0, 1.f);
  post_q_kernel<<<NTOK, 256, 0, stream>>>(C2b, fc, fs, qnope, qpe);
  gemm_bt<false><<<dim3(5, NTOK / 128, 1), 256, 0, stream>>>(
      x_bf, wkva_b, C1, NTOK, 576, DIM, DIM, DIM, 576, 0, 0, 0, 1.f);
  post_kv_kernel<<<NTOK, 256, 0, stream>>>(C1, kvnw, fc, fs, kv_sw, kvt, kpe_sw);
  // q_lat pre-scaled by SCALE_ (softmax scale folded into Q)
  gemm_bt<true><<<dim3(KVR / 128, NTOK / 128, NH), 256, 0, stream>>>(
      qnope, wbkt, qlat, NTOK, KVR, NOPE, NOPE, NOPE, KVR,
      (long)NTOK * NOPE, (long)KVR * NOPE, (long)NTOK * KVR, SCALE_);
  attn_kernel<<<dim3(512, 1, 1), 512, 0, stream>>>(
      qlat, qpe, kv_sw, kvt, kpe_sw, olat);
  gemm_bt<true><<<dim3(1, NTOK / 128, NH), 256, 0, stream>>>(
      olat, wbv, oflat, NTOK, VH, KVR, KVR, KVR, DIM,
      (long)NTOK * KVR, (long)VH * KVR, (long)VH, 1.f);
  gemm_bt<false><<<dim3(DIM / 128, NTOK / 128, 1), 256, 0, stream>>>(
      oflat, wo_b, out, NTOK, DIM, DIM, DIM, DIM, DIM, 0, 0, 0, 1.f);
}

// Round 6
// 540.697 us; speedup vs baseline: 1.8507x; 1.8507x over previous
//
#include <hip/hip_runtime.h>
#include <hip/hip_bf16.h>
#include <stdint.h>

#define BB 4
#define SS 1024
#define DIM 2048
#define NH 16
#define QR 1024
#define KVR 512
#define NOPE 128
#define ROPE 64
#define VH 128
#define QKH 192
#define NTOK 4096

static constexpr float SCALE_ = 0.07216878364870322f; // 192^-0.5
static constexpr float EPS_ = 1e-6f;

typedef unsigned short u16;
typedef unsigned int u32;
using f32x4  = __attribute__((ext_vector_type(4))) float;
using bf16x8 = __attribute__((ext_vector_type(8))) __bf16;

#define MFMA16 __builtin_amdgcn_mfma_f32_16x16x32_bf16

__device__ __forceinline__ u16 f2b(float f) {
  u32 u = __float_as_uint(f);
  u32 r = u + 0x7fffu + ((u >> 16) & 1u);   // RNE
  return (u16)(r >> 16);
}
__device__ __forceinline__ u32 pk2(float a, float b) {
  return (u32)f2b(a) | ((u32)f2b(b) << 16);
}
__device__ __forceinline__ float b2f(u32 hi16) {
  return __uint_as_float(hi16 << 16);
}

// ---------------- f32 -> bf16 convert (8 elems/thread) ----------------
__global__ __launch_bounds__(256) void cvt_bf16(const float* __restrict__ in,
                                                u16* __restrict__ out, int n) {
  int i = (blockIdx.x * 256 + threadIdx.x) * 8;
  if (i >= n) return;
  float4 a = *(const float4*)&in[i];
  float4 b = *(const float4*)&in[i + 4];
  uint4 o;
  o.x = pk2(a.x, a.y); o.y = pk2(a.z, a.w);
  o.z = pk2(b.x, b.y); o.w = pk2(b.z, b.w);
  *(uint4*)&out[i] = o;
}

// ---------------- wkv_b split: wb_k transposed per head, wb_v straight ----------------
__global__ __launch_bounds__(256) void prep_wkvb(const float* __restrict__ w,
                                                 u16* __restrict__ wbkt,
                                                 u16* __restrict__ wbv) {
  int idx = blockIdx.x * 256 + threadIdx.x;   // over 16*256*512
  int c = idx & 511;
  int rowh = idx >> 9;
  int h = rowh >> 8;
  int dr = rowh & 255;
  float v = w[idx];
  if (dr < NOPE) wbkt[((h * KVR + c) << 7) + dr] = f2b(v);           // (NH,512,128)
  else           wbv[((h * VH + (dr - NOPE)) << 9) + c] = f2b(v);    // (NH,128,512)
}

// ---------------- RMSNorm over 1024 (q path) ----------------
__global__ __launch_bounds__(256) void rms_q_kernel(const float* __restrict__ X,
                                                    const float* __restrict__ w,
                                                    u16* __restrict__ out) {
  int r = blockIdx.x, tid = threadIdx.x;
  const float4 v = *(const float4*)&X[(long)r * QR + tid * 4];
  float ss = v.x * v.x + v.y * v.y + v.z * v.z + v.w * v.w;
  for (int m = 1; m < 64; m <<= 1) ss += __shfl_xor(ss, m);
  __shared__ float red[4];
  if ((tid & 63) == 0) red[tid >> 6] = ss;
  __syncthreads();
  float tot = red[0] + red[1] + red[2] + red[3];
  float sc = rsqrtf(tot / QR + EPS_);
  float4 wv = *(const float4*)&w[tid * 4];
  uint2 o;
  o.x = pk2(v.x * sc * wv.x, v.y * sc * wv.y);
  o.y = pk2(v.z * sc * wv.z, v.w * sc * wv.w);
  *(uint2*)&out[(long)r * QR + tid * 4] = o;
}

// ---------------- q post (bf16 input): split nope / rope(pe)*SCALE, head-major ----------------
__global__ __launch_bounds__(256) void post_q_kernel(const u16* __restrict__ C2,
                                                     const float* __restrict__ fc,
                                                     const float* __restrict__ fs,
                                                     u16* __restrict__ qn,
                                                     u16* __restrict__ qp) {
  int r = blockIdx.x, tid = threadIdx.x;
  int s = r & (SS - 1);
  const u16* row = C2 + (long)r * (NH * QKH);
  for (int j = tid; j < NH * QKH / 2; j += 256) {
    int col = j * 2;
    int h = col / QKH;
    int dd = col - h * QKH;
    u32 pair = *(const u32*)&row[col];
    if (dd < NOPE) {
      *(u32*)&qn[((long)h * NTOK + r) * NOPE + dd] = pair;   // already bf16
    } else {
      float x0 = b2f(pair & 0xffffu), x1 = b2f(pair >> 16);
      int jr = (dd - NOPE) >> 1;
      float c = fc[s * 32 + jr], sn = fs[s * 32 + jr];
      *(u32*)&qp[((long)h * NTOK + r) * ROPE + (dd - NOPE)] =
          pk2((x0 * c - x1 * sn) * SCALE_, (x0 * sn + x1 * c) * SCALE_);
    }
  }
}

// ---------------- kv post: rmsnorm(512) -> kv_sw (XOR-swizzled) + kv^T, rope k_pe_sw ----------------
// Swizzle: element index d' = d ^ ((t&7)<<3) within each row.
__global__ __launch_bounds__(256) void post_kv_kernel(const float* __restrict__ C3,
                                                      const float* __restrict__ w,
                                                      const float* __restrict__ fc,
                                                      const float* __restrict__ fs,
                                                      u16* __restrict__ kv_sw,
                                                      u16* __restrict__ kvt,
                                                      u16* __restrict__ kpe_sw) {
  int r = blockIdx.x, tid = threadIdx.x;
  int b = r >> 10, t = r & (SS - 1);
  const float* row = C3 + (long)r * 576;
  float2 v = *(const float2*)&row[tid * 2];
  float ss = v.x * v.x + v.y * v.y;
  for (int m = 1; m < 64; m <<= 1) ss += __shfl_xor(ss, m);
  __shared__ float red[4];
  if ((tid & 63) == 0) red[tid >> 6] = ss;
  __syncthreads();
  float tot = red[0] + red[1] + red[2] + red[3];
  float sc = rsqrtf(tot / KVR + EPS_);
  int c = tid * 2;
  int xm = (t & 7) << 3;
  float y0 = v.x * sc * w[c], y1 = v.y * sc * w[c + 1];
  *(u32*)&kv_sw[((long)b * SS + t) * KVR + (c ^ xm)] = pk2(y0, y1);
  kvt[((long)b * KVR + c) * SS + t] = f2b(y0);
  kvt[((long)b * KVR + c + 1) * SS + t] = f2b(y1);
  if (tid < 32) {
    float x0 = row[KVR + tid * 2], x1 = row[KVR + tid * 2 + 1];
    float cc = fc[t * 32 + tid], sn = fs[t * 32 + tid];
    *(u32*)&kpe_sw[((long)b * SS + t) * ROPE + ((tid * 2) ^ xm)] =
        pk2(x0 * cc - x1 * sn, x0 * sn + x1 * cc);
  }
}

// ---------------- GEMM: C(M,N) = A(M,K) * B(N,K)^T, bf16 in, f32/bf16 out ----------------
template <bool CBF16>
__global__ __launch_bounds__(256) void gemm_bt(const u16* __restrict__ Ag,
                                               const u16* __restrict__ Bg,
                                               void* __restrict__ Cg,
                                               int M, int N, int K,
                                               int lda, int ldb, int ldc,
                                               long sA, long sB, long sC,
                                               float oscale) {
  const u16* A = Ag + (long)blockIdx.z * sA;
  const u16* Bm = Bg + (long)blockIdx.z * sB;
  const int row0 = blockIdx.y * 128;
  const int col0 = blockIdx.x * 128;
  const int tid = threadIdx.x;
  const int wave = tid >> 6, lane = tid & 63;
  const int g = lane >> 4, r = lane & 15;
  const int wr = wave >> 1, wc = wave & 1;

  __shared__ u16 As[2][128 * 32];
  __shared__ u16 Bs[2][128 * 32];

  f32x4 acc[4][4] = {};
  const int nk = K >> 5;

  auto stage = [&](int kt, int p) {
    int k0 = kt << 5;
#pragma unroll
    for (int j = 0; j < 2; ++j) {
      int ldsoff = (j * 4096 + wave * 1024) >> 1;
      int rowi = j * 64 + wave * 16 + (lane >> 2);
      int coli = (lane & 3) << 3;
      const u16* ga = A + (long)(row0 + rowi) * lda + k0 + coli;
      __builtin_amdgcn_global_load_lds(
          (const __attribute__((address_space(1))) void*)ga,
          (__attribute__((address_space(3))) void*)(&As[p][ldsoff]), 16, 0, 0);
      int rb = col0 + rowi; if (rb > N - 1) rb = N - 1;
      const u16* gb = Bm + (long)rb * ldb + k0 + coli;
      __builtin_amdgcn_global_load_lds(
          (const __attribute__((address_space(1))) void*)gb,
          (__attribute__((address_space(3))) void*)(&Bs[p][ldsoff]), 16, 0, 0);
    }
  };

  stage(0, 0);
  for (int kt = 0; kt < nk; ++kt) {
    __syncthreads();
    if (kt + 1 < nk) stage(kt + 1, (kt + 1) & 1);
    const int p = kt & 1;
    bf16x8 af[4], bf[4];
#pragma unroll
    for (int i = 0; i < 4; i++) {
      af[i] = *(const bf16x8*)&As[p][(wr * 64 + i * 16 + r) * 32 + g * 8];
      bf[i] = *(const bf16x8*)&Bs[p][(wc * 64 + i * 16 + r) * 32 + g * 8];
    }
#pragma unroll
    for (int i = 0; i < 4; i++)
#pragma unroll
      for (int j = 0; j < 4; j++)
        acc[i][j] = MFMA16(af[i], bf[j], acc[i][j], 0, 0, 0);
  }

#pragma unroll
  for (int i = 0; i < 4; i++)
#pragma unroll
    for (int j = 0; j < 4; j++) {
      int rowb = row0 + wr * 64 + i * 16 + g * 4;
      int colc = col0 + wc * 64 + j * 16 + r;
      if (colc < N) {
        if constexpr (CBF16) {
          u16* C = (u16*)Cg + (long)blockIdx.z * sC;
#pragma unroll
          for (int e = 0; e < 4; e++)
            C[(long)(rowb + e) * ldc + colc] = f2b(acc[i][j][e] * oscale);
        } else {
          float* C = (float*)Cg + (long)blockIdx.z * sC;
#pragma unroll
          for (int e = 0; e < 4; e++)
            C[(long)(rowb + e) * ldc + colc] = acc[i][j][e] * oscale;
        }
      }
    }
}

// ---------------- flash attention v6 (round-4 structure, KVBLK=64) ----------------
// 256 blocks, batch pinned to XCD pair, 2 balanced 128-row chunks per block.
// 8 waves: QK per-wave 16 rows (Q in regs), keys in 64-wide LDS tiles;
// PV all-rows x own 64 V-cols. 2 barriers per 64-key tile.
__global__ __launch_bounds__(512) void attn_kernel(
    const u16* __restrict__ q_lat, const u16* __restrict__ q_pe,
    const u16* __restrict__ kv_sw, const u16* __restrict__ kvt,
    const u16* __restrict__ kpe_sw, u16* __restrict__ o_lat) {
  const int bid = blockIdx.x;
  const int xcd = bid & 7, idx = bid >> 3;
  const int b = xcd >> 1;
  const int h = idx & 15;
  const int jp = ((xcd & 1) << 1) | (idx >> 4);   // 0..3
  const int wv = threadIdx.x >> 6, lane = threadIdx.x & 63;
  const int g = lane >> 4, r = lane & 15;
  const int xm = (r & 7) << 3;

  __shared__ __attribute__((aligned(16))) u16 Ks[64 * 512];   // 64 KB swizzled K tile
  __shared__ __attribute__((aligned(16))) u16 P[128][72];     // 18 KB (+16B pad/row)
  __shared__ __attribute__((aligned(16))) float alphab[128];
  __shared__ __attribute__((aligned(16))) float lbuf[128];

  const u16* KVg = kv_sw + (long)b * SS * KVR;
  const u16* KPg = kpe_sw + (long)b * SS * ROPE;
  const u16* KT  = kvt + (long)b * KVR * SS;

  auto stage = [&](int t0) {
#pragma unroll
    for (int i = 0; i < 8; ++i) {
      int row = wv * 8 + i;
      const u16* ga = KVg + (long)(t0 + row) * KVR + lane * 8;
      __builtin_amdgcn_global_load_lds(
          (const __attribute__((address_space(1))) void*)ga,
          (__attribute__((address_space(3))) void*)(&Ks[row * 512]), 16, 0, 0);
    }
  };

  for (int seg = 0; seg < 2; ++seg) {
    const int jc = seg ? (7 - jp) : jp;
    const int qa = jc * 128;
    const int nt = (qa >> 6) + 2;          // tiles of 64 keys
    const int q_row = qa + wv * 16 + r;

    const u16* Q  = q_lat + ((long)h * NTOK + (long)b * SS + q_row) * KVR;
    const u16* Qp = q_pe  + ((long)h * NTOK + (long)b * SS + q_row) * ROPE;
    bf16x8 qf[16];
#pragma unroll
    for (int c = 0; c < 16; ++c) qf[c] = *(const bf16x8*)&Q[c * 32 + g * 8];

    f32x4 acc[8][4];
#pragma unroll
    for (int i = 0; i < 8; i++)
#pragma unroll
      for (int jn = 0; jn < 4; jn++) acc[i][jn] = f32x4{0.f, 0.f, 0.f, 0.f};
    float m_run = -1e30f, l_run = 0.f;

    stage(0);
    __syncthreads();

    for (int tt = 0; tt < nt; ++tt) {
      const int t0 = tt << 6;

      // QK^T over 64 keys (4 row-groups of 16)
      f32x4 st[4];
#pragma unroll
      for (int jn = 0; jn < 4; jn++) st[jn] = f32x4{0.f, 0.f, 0.f, 0.f};
#pragma unroll
      for (int c = 0; c < 16; ++c) {
        int ix = (c * 32 + g * 8) ^ xm;
        bf16x8 k0 = *(const bf16x8*)&Ks[r * 512 + ix];
        bf16x8 k1 = *(const bf16x8*)&Ks[(16 + r) * 512 + ix];
        bf16x8 k2 = *(const bf16x8*)&Ks[(32 + r) * 512 + ix];
        bf16x8 k3 = *(const bf16x8*)&Ks[(48 + r) * 512 + ix];
        st[0] = MFMA16(k0, qf[c], st[0], 0, 0, 0);
        st[1] = MFMA16(k1, qf[c], st[1], 0, 0, 0);
        st[2] = MFMA16(k2, qf[c], st[2], 0, 0, 0);
        st[3] = MFMA16(k3, qf[c], st[3], 0, 0, 0);
      }
#pragma unroll
      for (int c = 0; c < 2; ++c) {
        bf16x8 qpv = *(const bf16x8*)&Qp[c * 32 + g * 8];
        int ix = (c * 32 + g * 8) ^ xm;
        bf16x8 k0 = *(const bf16x8*)&KPg[(long)(t0 + r) * ROPE + ix];
        bf16x8 k1 = *(const bf16x8*)&KPg[(long)(t0 + 16 + r) * ROPE + ix];
        bf16x8 k2 = *(const bf16x8*)&KPg[(long)(t0 + 32 + r) * ROPE + ix];
        bf16x8 k3 = *(const bf16x8*)&KPg[(long)(t0 + 48 + r) * ROPE + ix];
        st[0] = MFMA16(k0, qpv, st[0], 0, 0, 0);
        st[1] = MFMA16(k1, qpv, st[1], 0, 0, 0);
        st[2] = MFMA16(k2, qpv, st[2], 0, 0, 0);
        st[3] = MFMA16(k3, qpv, st[3], 0, 0, 0);
      }

      // softmax over 16 lane-local scores (keys t0 + jn*16 + g*4 + i)
      float smax = -1e30f;
#pragma unroll
      for (int jn = 0; jn < 4; jn++)
#pragma unroll
        for (int i = 0; i < 4; i++) {
          int t = t0 + jn * 16 + g * 4 + i;
          st[jn][i] = (t <= q_row) ? st[jn][i] : -1e30f;
          smax = fmaxf(smax, st[jn][i]);
        }
      smax = fmaxf(smax, __shfl_xor(smax, 16));
      smax = fmaxf(smax, __shfl_xor(smax, 32));
      float m_new = fmaxf(m_run, smax);
      float alpha = __expf(m_run - m_new);
      float ps = 0.f;
#pragma unroll
      for (int jn = 0; jn < 4; jn++) {
        float p0 = (st[jn][0] < -1e29f) ? 0.f : __expf(st[jn][0] - m_new);
        float p1 = (st[jn][1] < -1e29f) ? 0.f : __expf(st[jn][1] - m_new);
        float p2 = (st[jn][2] < -1e29f) ? 0.f : __expf(st[jn][2] - m_new);
        float p3 = (st[jn][3] < -1e29f) ? 0.f : __expf(st[jn][3] - m_new);
        ps += (p0 + p1) + (p2 + p3);
        uint2 w;
        w.x = pk2(p0, p1); w.y = pk2(p2, p3);
        *(uint2*)&P[wv * 16 + r][jn * 16 + g * 4] = w;
      }
      ps += __shfl_xor(ps, 16);
      ps += __shfl_xor(ps, 32);
      l_run = l_run * alpha + ps;
      m_run = m_new;
      if (g == 0) alphab[wv * 16 + r] = alpha;
      __syncthreads();                     // B1: P/alpha visible; Ks reads retired
      if (tt + 1 < nt) stage(t0 + 64);     // overwrite Ks; drained at B2

      // PV: all 128 rows x own 64 cols, 64 keys in two 32-key halves
#pragma unroll
      for (int ks = 0; ks < 2; ++ks) {
        bf16x8 vf[4];
#pragma unroll
        for (int nc = 0; nc < 4; ++nc)
          vf[nc] = *(const bf16x8*)&KT[(long)(wv * 64 + nc * 16 + r) * SS +
                                       t0 + ks * 32 + g * 8];
#pragma unroll
        for (int mc = 0; mc < 8; ++mc) {
          bf16x8 pa = *(const bf16x8*)&P[mc * 16 + r][ks * 32 + g * 8];
          if (ks == 0) {
            f32x4 a4 = *(const f32x4*)&alphab[mc * 16 + g * 4];
#pragma unroll
            for (int nc = 0; nc < 4; ++nc) {
              f32x4 t = acc[mc][nc] * a4;
              acc[mc][nc] = MFMA16(pa, vf[nc], t, 0, 0, 0);
            }
          } else {
#pragma unroll
            for (int nc = 0; nc < 4; ++nc)
              acc[mc][nc] = MFMA16(pa, vf[nc], acc[mc][nc], 0, 0, 0);
          }
        }
      }
      __syncthreads();                     // B2: stage drained; P safe to rewrite
    }

    if (g == 0) lbuf[wv * 16 + r] = l_run;
    __syncthreads();
    u16* O = o_lat + ((long)h * NTOK + (long)b * SS + qa) * KVR;
#pragma unroll
    for (int mc = 0; mc < 8; ++mc) {
      f32x4 li = *(const f32x4*)&lbuf[mc * 16 + g * 4];
#pragma unroll
      for (int e = 0; e < 4; e++) li[e] = 1.f / li[e];
#pragma unroll
      for (int nc = 0; nc < 4; ++nc) {
        int col = wv * 64 + nc * 16 + r;
#pragma unroll
        for (int e = 0; e < 4; e++)
          O[(long)(mc * 16 + g * 4 + e) * KVR + col] = f2b(acc[mc][nc][e] * li[e]);
      }
    }
    __syncthreads();                       // lbuf/Ks safe for next seg
  }
}

// ---------------- host launch ----------------
extern "C" void kernel_launch(void* const* d_in, const int* in_sizes, int n_in,
                              void* d_out, int out_size, void* d_ws, size_t ws_size,
                              hipStream_t stream) {
  (void)in_sizes; (void)n_in; (void)out_size; (void)ws_size;
  const float* x    = (const float*)d_in[0];
  const float* fc   = (const float*)d_in[2];
  const float* fs   = (const float*)d_in[3];
  const float* wqa  = (const float*)d_in[4];
  const float* qnw  = (const float*)d_in[5];
  const float* wqb  = (const float*)d_in[6];
  const float* wkva = (const float*)d_in[7];
  const float* kvnw = (const float*)d_in[8];
  const float* wkvb = (const float*)d_in[9];
  const float* wo   = (const float*)d_in[10];
  float* out = (float*)d_out;

  char* w = (char*)d_ws;
  size_t off = 0;
  auto alloc = [&](size_t bytes) {
    void* p = w + off;
    off += (bytes + 255) & ~(size_t)255;
    return p;
  };
  // ---- persistent region ----
  u16* wbkt   = (u16*)alloc((size_t)NH * KVR * NOPE * 2);
  u16* wbv    = (u16*)alloc((size_t)NH * VH * KVR * 2);
  u16* wo_b   = (u16*)alloc((size_t)DIM * DIM * 2);
  u16* qnope  = (u16*)alloc((size_t)NH * NTOK * NOPE * 2);
  u16* qpe    = (u16*)alloc((size_t)NH * NTOK * ROPE * 2);
  u16* kv_sw  = (u16*)alloc((size_t)BB * SS * KVR * 2);
  u16* kvt    = (u16*)alloc((size_t)BB * KVR * SS * 2);
  u16* kpe_sw = (u16*)alloc((size_t)BB * SS * ROPE * 2);
  u16* oflat  = (u16*)alloc((size_t)NTOK * DIM * 2);
  // ---- transient region, later overlaid by qlat/olat ----
  u16* qlat   = (u16*)(w + off);            // overlay base
  u16* olat   = qlat;                       // attention writes O in-place over Q
  u16* x_bf   = (u16*)alloc((size_t)NTOK * DIM * 2);
  u16* wqa_b  = (u16*)alloc((size_t)QR * DIM * 2);
  u16* wqb_b  = (u16*)alloc((size_t)NH * QKH * QR * 2);
  u16* wkva_b = (u16*)alloc((size_t)576 * DIM * 2);
  u16* qn     = (u16*)alloc((size_t)NTOK * QR * 2);
  float* C1   = (float*)alloc((size_t)NTOK * QR * 4);
  u16* C2b    = (u16*)alloc((size_t)NTOK * NH * QKH * 2);

  cvt_bf16<<<(NTOK * DIM) / 2048, 256, 0, stream>>>(x, x_bf, NTOK * DIM);
  cvt_bf16<<<(QR * DIM) / 2048, 256, 0, stream>>>(wqa, wqa_b, QR * DIM);
  cvt_bf16<<<(NH * QKH * QR) / 2048, 256, 0, stream>>>(wqb, wqb_b, NH * QKH * QR);
  cvt_bf16<<<(576 * DIM) / 2048, 256, 0, stream>>>(wkva, wkva_b, 576 * DIM);
  cvt_bf16<<<(DIM * DIM) / 2048, 256, 0, stream>>>(wo, wo_b, DIM * DIM);
  prep_wkvb<<<(NH * 256 * KVR) / 256, 256, 0, stream>>>(wkvb, wbkt, wbv);

  gemm_bt<false><<<dim3(QR / 128, NTOK / 128, 1), 256, 0, stream>>>(
      x_bf, wqa_b, C1, NTOK, QR, DIM, DIM, DIM, QR, 0, 0, 0, 1.f);
  rms_q_kernel<<<NTOK, 256, 0, stream>>>(C1, qnw, qn);
  gemm_bt<true><<<dim3(NH * QKH / 128, NTOK / 128, 1), 256, 0, stream>>>(
      qn, wqb_b, C2b, NTOK, NH * QKH, QR, QR, QR, NH * QKH, 0, 0, 0, 1.f);
  post_q_kernel<<<NTOK, 256, 0, stream>>>(C2b, fc, fs, qnope, qpe);
  gemm_bt<false><<<dim3(5, NTOK / 128, 1), 256, 0, stream>>>(
      x_bf, wkva_b, C1, NTOK, 576, DIM, DIM, DIM, 576, 0, 0, 0, 1.f);
  post_kv_kernel<<<NTOK, 256, 0, stream>>>(C1, kvnw, fc, fs, kv_sw, kvt, kpe_sw);
  // q_lat pre-scaled by SCALE_ (softmax scale folded into Q)
  gemm_bt<true><<<dim3(KVR / 128, NTOK / 128, NH), 256, 0, stream>>>(
      qnope, wbkt, qlat, NTOK, KVR, NOPE, NOPE, NOPE, KVR,
      (long)NTOK * NOPE, (long)KVR * NOPE, (long)NTOK * KVR, SCALE_);
  attn_kernel<<<dim3(256, 1, 1), 512, 0, stream>>>(
      qlat, qpe, kv_sw, kvt, kpe_sw, olat);
  gemm_bt<true><<<dim3(1, NTOK / 128, NH), 256, 0, stream>>>(
      olat, wbv, oflat, NTOK, VH, KVR, KVR, KVR, DIM,
      (long)NTOK * KVR, (long)VH * KVR, (long)VH, 1.f);
  gemm_bt<false><<<dim3(DIM / 128, NTOK / 128, 1), 256, 0, stream>>>(
      oflat, wo_b, out, NTOK, DIM, DIM, DIM, DIM, DIM, 0, 0, 0, 1.f);
}